// Round 3
// baseline (245.137 us; speedup 1.0000x reference)
//
#include <hip/hip_runtime.h>
#include <hip/hip_bf16.h>

#define K_CLS 20
#define HIN 480
#define WIN 640
#define NPIX (HIN * WIN)
#define C_ 512
#define H_ 30
#define W_ 40
#define NB_ 5
#define CNT_THRESH 10000
// out layout (fp32): pool_x[2048], NB, N, x_cropped[6*4*512*30*40]
#define XCROP_ELEMS (6 * 4 * C_ * H_ * W_)
#define OUT_TOTAL (2050 + XCROP_ELEMS)

// ws layout (ints): cnt[20], minx[20], miny[20], maxx[20], maxy[20], node_boxes[5*4]

__global__ void init_k(int* __restrict__ ws) {
    int t = threadIdx.x;
    if (t < K_CLS) {
        ws[t]      = 0;     // count
        ws[20 + t] = WIN;   // min x
        ws[40 + t] = HIN;   // min y
        ws[60 + t] = -1;    // max x
        ws[80 + t] = -1;    // max y
    }
}

__global__ void stats_k(const float* __restrict__ seg, int* __restrict__ ws) {
    __shared__ int s_cnt[K_CLS], s_mnx[K_CLS], s_mny[K_CLS], s_mxx[K_CLS], s_mxy[K_CLS];
    int t = threadIdx.x;
    if (t < K_CLS) { s_cnt[t] = 0; s_mnx[t] = WIN; s_mny[t] = HIN; s_mxx[t] = -1; s_mxy[t] = -1; }
    __syncthreads();
    int pix = blockIdx.x * blockDim.x + t;
    if (pix < NPIX) {
        // only batch element 3 matters (mask = argmax(...)[-1])
        const float* base = seg + (size_t)3 * K_CLS * NPIX + pix;
        float best = base[0];
        int bk = 0;
        #pragma unroll
        for (int k = 1; k < K_CLS; k++) {
            float v = base[(size_t)k * NPIX];
            if (v > best) { best = v; bk = k; }   // strict > : np.argmax first-max tie-break
        }
        int x = pix % WIN, y = pix / WIN;
        atomicAdd(&s_cnt[bk], 1);
        atomicMin(&s_mnx[bk], x);
        atomicMin(&s_mny[bk], y);
        atomicMax(&s_mxx[bk], x);
        atomicMax(&s_mxy[bk], y);
    }
    __syncthreads();
    if (t < K_CLS && s_cnt[t] > 0) {
        atomicAdd(&ws[t], s_cnt[t]);
        atomicMin(&ws[20 + t], s_mnx[t]);
        atomicMin(&ws[40 + t], s_mny[t]);
        atomicMax(&ws[60 + t], s_mxx[t]);
        atomicMax(&ws[80 + t], s_mxy[t]);
    }
}

__global__ void plan_k(int* __restrict__ ws) {
    if (threadIdx.x != 0 || blockIdx.x != 0) return;
    int* cnt = ws;
    int* mnx = ws + 20; int* mny = ws + 40; int* mxx = ws + 60; int* mxy = ws + 80;
    int* nb  = ws + 100;   // 5 boxes * 4 ints (x0,y0,x1,y1)

    // np.unique -> sorted present ids; drop ids[0] (smallest present)
    int firstp = -1;
    for (int i = 0; i < K_CLS; i++) if (cnt[i] > 0) { firstp = i; break; }
    int order[K_CLS]; int nc = 0;
    for (int i = 0; i < K_CLS; i++)
        if (cnt[i] > 0 && i != firstp) order[nc++] = i;

    // stable insertion sort, descending by count (tie -> smaller id first)
    for (int i = 1; i < nc; i++) {
        int key = order[i]; int j = i - 1;
        while (j >= 0 && cnt[order[j]] < cnt[key]) { order[j + 1] = order[j]; j--; }
        order[j + 1] = key;
    }

    // sel = top (NB-2) ranks with count > thresh, in rank order
    int nsel = 0;
    for (int i = 0; i < nc && nsel < NB_ - 2; i++) {
        int b = order[i];
        if (cnt[b] > CNT_THRESH) {
            nb[nsel * 4 + 0] = mnx[b] >> 4;   // /16 then int-trunc (non-negative)
            nb[nsel * 4 + 1] = mny[b] >> 4;
            nb[nsel * 4 + 2] = mxx[b] >> 4;
            nb[nsel * 4 + 3] = mxy[b] >> 4;
            nsel++;
        }
    }
    // fallback boxes bb[0..] fill remaining slots
    const int bb[5][4] = {
        {W_ / 4, H_ / 4, 3 * W_ / 4, 3 * H_ / 4},
        {0, 0, W_ / 3, H_},
        {0, 0, W_, H_ / 3},
        {2 * W_ / 3, 0, W_, H_},
        {0, 2 * H_ / 3, W_, H_}
    };
    for (int i = 0; nsel < NB_; i++, nsel++) {
        nb[nsel * 4 + 0] = bb[i][0];
        nb[nsel * 4 + 1] = bb[i][1];
        nb[nsel * 4 + 2] = bb[i][2];
        nb[nsel * 4 + 3] = bb[i][3];
    }
}

__global__ void out_k(const float* __restrict__ feat,
                      const float* __restrict__ pool_x,
                      const int* __restrict__ nb,
                      float* __restrict__ out) {
    int idx = blockIdx.x * blockDim.x + threadIdx.x;
    if (idx >= OUT_TOTAL) return;
    if (idx < 2048) { out[idx] = pool_x[idx]; return; }
    if (idx == 2048) { out[idx] = 5.0f; return; }  // NB
    if (idx == 2049) { out[idx] = 4.0f; return; }  // N
    int j = idx - 2050;
    int w  = j % W_;
    int t1 = j / W_;
    int h  = t1 % H_;
    int t2 = t1 / H_;
    int c  = t2 % C_;
    int sn = t2 / C_;              // linear index over (s,n): s*4 + n, 0..23

    if (sn >= 20) {                // s == 5 -> raw feat copy
        int n = sn - 20;
        out[idx] = feat[((size_t)(n * C_ + c) * H_ + h) * W_ + w];
        return;
    }
    // reshape (4,5,...)->(5,4,...): linear L -> node b = L%5, batch n2 = L/5
    int b  = sn % NB_;
    int n2 = sn / NB_;
    int x0 = nb[b * 4 + 0], y0 = nb[b * 4 + 1];
    int x1 = nb[b * 4 + 2], y1 = nb[b * 4 + 3];
    int iw = x1 - x0; if (iw < 1) iw = 1;
    int ih = y1 - y0; if (ih < 1) ih = 1;

    const float* src = feat + (size_t)(n2 * C_ + c) * H_ * W_;

    // jax.image.resize 'bilinear', half-pixel centers; scale >= 1 here so
    // antialias is inert and edge renormalization == index clamping.
    float fy = (h + 0.5f) * (float)ih / (float)H_ - 0.5f;
    float fx = (w + 0.5f) * (float)iw / (float)W_ - 0.5f;
    float flY = floorf(fy), flX = floorf(fx);
    float ty = fy - flY, tx = fx - flX;
    int ylo = (int)flY, xlo = (int)flX;
    int yhi = ylo + 1, xhi = xlo + 1;
    ylo = ylo < 0 ? 0 : (ylo > ih - 1 ? ih - 1 : ylo);
    yhi = yhi < 0 ? 0 : (yhi > ih - 1 ? ih - 1 : yhi);
    xlo = xlo < 0 ? 0 : (xlo > iw - 1 ? iw - 1 : xlo);
    xhi = xhi < 0 ? 0 : (xhi > iw - 1 ? iw - 1 : xhi);

    int r0 = (y0 + ylo) * W_, r1 = (y0 + yhi) * W_;
    float v00 = src[r0 + x0 + xlo];
    float v01 = src[r0 + x0 + xhi];
    float v10 = src[r1 + x0 + xlo];
    float v11 = src[r1 + x0 + xhi];
    float val = (1.0f - ty) * ((1.0f - tx) * v00 + tx * v01)
              +         ty  * ((1.0f - tx) * v10 + tx * v11);
    out[idx] = val;
}

extern "C" void kernel_launch(void* const* d_in, const int* in_sizes, int n_in,
                              void* d_out, int out_size, void* d_ws, size_t ws_size,
                              hipStream_t stream) {
    const float* seg    = (const float*)d_in[0];
    const float* feat   = (const float*)d_in[1];
    const float* pool_x = (const float*)d_in[2];
    float* out = (float*)d_out;
    int* ws = (int*)d_ws;

    init_k<<<1, 64, 0, stream>>>(ws);
    stats_k<<<(NPIX + 255) / 256, 256, 0, stream>>>(seg, ws);
    plan_k<<<1, 64, 0, stream>>>(ws);
    out_k<<<(OUT_TOTAL + 255) / 256, 256, 0, stream>>>(feat, pool_x, ws + 100, out);
}